// Round 16
// baseline (2049.504 us; speedup 1.0000x reference)
//
#include <hip/hip_runtime.h>
#include <hip/hip_bf16.h>
#include <math.h>

#define TT 512
#define BB 128
#define DD 256
#define HH 512
#define EPSF 1e-7f
#define NBG 8     // b-groups of 16 rows (independent LSTM chains)
#define NKS 16    // k-slices of 32 cols per b-group

typedef unsigned int u32;
typedef unsigned short u16;
typedef __attribute__((ext_vector_type(8))) short bf16x8;
typedef __attribute__((ext_vector_type(4))) float f32x4;
typedef __attribute__((ext_vector_type(4))) u32 u32x4;

__device__ __forceinline__ u16 f2b(float x){
  __hip_bfloat16 b = __float2bfloat16(x);
  union { __hip_bfloat16 h; u16 u; } c; c.h = b; return c.u;
}
__device__ __forceinline__ bf16x8 as_b8(u32x4 u){
  union { u32x4 a; bf16x8 b; } c; c.a = u; return c.b;
}
__device__ __forceinline__ float blo(u32 u){ return __uint_as_float(u << 16); }
__device__ __forceinline__ float bhi(u32 u){ return __uint_as_float(u & 0xffff0000u); }
__device__ __forceinline__ u32 bpack(float lo, float hi){
  return ((u32)f2b(hi) << 16) | (u32)f2b(lo);
}
// MALL-coherent ops (bypass L1+L2 both ways; zero cache-maintenance anywhere)
__device__ __forceinline__ u32x4 ld16s(const void* p){
  u32x4 r;
  asm volatile("global_load_dwordx4 %0, %1, off sc0 sc1" : "=v"(r) : "v"(p) : "memory");
  return r;
}
__device__ __forceinline__ void st4s(void* p, u32 v){
  asm volatile("global_store_dword %0, %1, off sc0 sc1" :: "v"(p), "v"(v) : "memory");
}
// plain cached ops (hand-counted vmem)
__device__ __forceinline__ u32x4 ld16p(const void* p){
  u32x4 r;
  asm volatile("global_load_dwordx4 %0, %1, off" : "=v"(r) : "v"(p) : "memory");
  return r;
}
__device__ __forceinline__ void st4p(void* p, u32 v){
  asm volatile("global_store_dword %0, %1, off" :: "v"(p), "v"(v) : "memory");
}
__device__ __forceinline__ void waitv0(){
  asm volatile("s_waitcnt vmcnt(0)" ::: "memory");
  __builtin_amdgcn_sched_barrier(0);
}
// retire everything older than the 4 in-flight data loads (4 xa + 2 stores)
__device__ __forceinline__ void waitv4(){
  asm volatile("s_waitcnt vmcnt(4)" ::: "memory");
  __builtin_amdgcn_sched_barrier(0);
}
// raw barrier: LDS visibility only — never drains vmcnt
__device__ __forceinline__ void bar_raw(){
  asm volatile("s_waitcnt lgkmcnt(0)" ::: "memory");
  __builtin_amdgcn_sched_barrier(0);
  __builtin_amdgcn_s_barrier();
  __builtin_amdgcn_sched_barrier(0);
}

// ---------------------------------------------------------------------------
// Setup: masks zx/zh, combined bias, bf16 Wx/Wh, hmraw tag-invalidation.
// ---------------------------------------------------------------------------
__global__ void setup_kernel(const float* __restrict__ ux, const float* __restrict__ uh,
                             const float* __restrict__ p_logit,
                             const float* __restrict__ bx, const float* __restrict__ bh,
                             const float* __restrict__ Wx, const float* __restrict__ Wh,
                             float* __restrict__ zx, float* __restrict__ zh,
                             float* __restrict__ bias,
                             u16* __restrict__ wxb, u16* __restrict__ whb,
                             u32* __restrict__ hmraw){
  const int i = blockIdx.x*256 + threadIdx.x;
  const float p = 1.0f/(1.0f+expf(-p_logit[0]));
  const float lp = logf(p+EPSF) - logf(1.0f-p+EPSF);
  const float inv1mp = 1.0f/(1.0f-p);
  const int S1 = 4*BB*DD;             // zx end      131072
  const int S2 = S1 + 4*BB*HH;        // zh end      393216
  const int S3 = S2 + 4*HH;           // bias end    395264
  const int S4 = S3 + 4*HH*DD;        // wxb end     919552
  const int S5 = S4 + 4*HH*HH;        // whb end     1968128
  const int S6 = S5 + 2*NBG*16*HH;    // hmraw end   2099200
  if (i < S1){
    float u = ux[i];
    float l = (lp + logf(u+EPSF) - logf(1.0f-u+EPSF)) * 10.0f;  // /TEMP
    zx[i] = (1.0f - 1.0f/(1.0f+expf(-l))) * inv1mp;
  } else if (i < S2){
    int j = i - S1;
    float u = uh[j];
    float l = (lp + logf(u+EPSF) - logf(1.0f-u+EPSF)) * 10.0f;
    zh[j] = (1.0f - 1.0f/(1.0f+expf(-l))) * inv1mp;
  } else if (i < S3){
    int j = i - S2;
    bias[j] = bx[j] + bh[j];
  } else if (i < S4){
    int j = i - S3;
    wxb[j] = f2b(Wx[j]);
  } else if (i < S5){
    int j = i - S4;
    whb[j] = f2b(Wh[j]);
  } else if (i < S6){
    hmraw[i - S5] = 0xFFFF0000u;   // invalid tag (kills cross-replay ghosts)
  }
}

// ---------------------------------------------------------------------------
// xim[t][g][b][d] = bf16(input[t][b][d] * zx[g][b][d]); input read once.
// ---------------------------------------------------------------------------
__global__ void xim_kernel(const float* __restrict__ input, const float* __restrict__ zx,
                           u16* __restrict__ xim){
  const int i = blockIdx.x*256 + threadIdx.x;   // (t,b,d-octet)
  const int d = (i & 31) * 8;
  const int rest = i >> 5;             // t*BB + b
  const int b = rest & (BB-1);
  const int t = rest >> 7;
  const float* ip = input + ((size_t)t*BB + b)*DD + d;
  const float4 x0 = *(const float4*)ip;
  const float4 x1 = *(const float4*)(ip+4);
  #pragma unroll
  for (int g = 0; g < 4; g++){
    const float* zp = zx + ((size_t)g*BB + b)*DD + d;
    const float4 z0 = *(const float4*)zp;
    const float4 z1 = *(const float4*)(zp+4);
    union { u16 s[8]; uint4 v; } o;
    o.s[0]=f2b(x0.x*z0.x); o.s[1]=f2b(x0.y*z0.y); o.s[2]=f2b(x0.z*z0.z); o.s[3]=f2b(x0.w*z0.w);
    o.s[4]=f2b(x1.x*z1.x); o.s[5]=f2b(x1.y*z1.y); o.s[6]=f2b(x1.z*z1.z); o.s[7]=f2b(x1.w*z1.w);
    *(uint4*)(xim + (((size_t)t*4 + g)*BB + b)*DD + d) = o.v;
  }
}

// ---------------------------------------------------------------------------
// Persistent LSTM: cooperative raw-h tagged exchange, detection fused into
// the cooperative read; speculative read issued in the PREVIOUS epilogue;
// barrier [C] removed (verify(t+1) subsumes it: passing requires own-block
// tag stores, which follow all pl/hsh reads in program order).
// 128 blocks = 8 bg x 16 ks; 512 thr = 8 waves = (gate g) x (K-half qh).
// ---------------------------------------------------------------------------
__global__ __launch_bounds__(512, 2)
void lstm_persist(const u16* __restrict__ xim,   // [T][4][B][D]
                  const u16* __restrict__ whb,   // [4][H][H]
                  const u16* __restrict__ wxb,   // [4][H][D]
                  const float* __restrict__ zh,  // [4][B][H]
                  const float* __restrict__ bias,// [4][H]
                  u32* __restrict__ hmraw,       // [2][NBG][16][H] tagged h
                  float* __restrict__ hn,        // [T][B][H]
                  float* __restrict__ htc)       // [2][B][H]
{
  __shared__ float pl[8][16][36];               // partial gates (padded)
  __shared__ __align__(16) u16 hsh[16][520];    // shared h(t-1) bf16 (padded)

  const int bid = blockIdx.x;
  const int bg = bid & 7, ks = bid >> 3;
  const int b0 = bg*16, k0 = ks*32;
  const int tid = threadIdx.x;
  const int wid = tid >> 6, lane = tid & 63;
  const int g = wid & 3, qh = wid >> 2;
  const int arow = lane & 15, kq = lane >> 4;

  // ---- weights into registers ----
  u32x4 whf[2][8], wxf[2][4];
  #pragma unroll
  for (int nt = 0; nt < 2; nt++){
    #pragma unroll
    for (int c = 0; c < 8; c++)
      whf[nt][c] = *(const u32x4*)(whb + (((size_t)g*HH + k0 + nt*16 + arow)*HH
                                          + qh*256 + c*32 + kq*8));
    #pragma unroll
    for (int c = 0; c < 4; c++)
      wxf[nt][c] = *(const u32x4*)(wxb + (((size_t)g*HH + k0 + nt*16 + arow)*DD
                                          + qh*128 + c*32 + kq*8));
  }

  // zh for this wave's A-slice, packed bf16
  u32x4 zf[8];
  {
    const float* zp = zh + ((size_t)g*BB + b0 + arow)*HH + qh*256 + kq*8;
    #pragma unroll
    for (int c = 0; c < 8; c++){
      zf[c].x = bpack(zp[c*32+0], zp[c*32+1]);
      zf[c].y = bpack(zp[c*32+2], zp[c*32+3]);
      zf[c].z = bpack(zp[c*32+4], zp[c*32+5]);
      zf[c].w = bpack(zp[c*32+6], zp[c*32+7]);
    }
  }

  // per-thread epilogue constants (1 cell per thread)
  const int ebl = tid >> 5, ekl = tid & 31;
  float bias4[4];
  #pragma unroll
  for (int gg = 0; gg < 4; gg++)
    bias4[gg] = bias[gg*HH + k0 + ekl];
  float creg = 0.f;

  // prologue: xa for t=0
  u32x4 xa[4], a0, a1, a2, a3;
  #pragma unroll
  for (int c = 0; c < 4; c++)
    xa[c] = ld16p(xim + (((size_t)g*BB + b0 + arow)*DD + qh*128 + c*32 + kq*8));
  waitv0();

  for (int t = 0; t < TT; t++){
    f32x4 acc0 = {0.f,0.f,0.f,0.f}, acc1 = {0.f,0.f,0.f,0.f};

    if (t > 0){
      // data loads were issued in the previous epilogue (newest 4 in queue)
      const u32* hb = hmraw + ((size_t)((t-1)&1)*NBG + bg)*(16*HH) + tid*16;
      waitv4();    // retires xa(4) + 2 stores (older); data stays in flight
      #pragma unroll
      for (int c = 0; c < 4; c++){
        acc0 = __builtin_amdgcn_mfma_f32_16x16x32_bf16(as_b8(xa[c]), as_b8(wxf[0][c]), acc0, 0,0,0);
        acc1 = __builtin_amdgcn_mfma_f32_16x16x32_bf16(as_b8(xa[c]), as_b8(wxf[1][c]), acc1, 0,0,0);
      }
      waitv0();    // data landed
      const u32 tw = (u32)(t-1) << 16;
      while (1){   // tags ARE the detection; paced wave-local retry
        u32 bad = (a0.x^tw)|(a0.y^tw)|(a0.z^tw)|(a0.w^tw)
                | (a1.x^tw)|(a1.y^tw)|(a1.z^tw)|(a1.w^tw)
                | (a2.x^tw)|(a2.y^tw)|(a2.z^tw)|(a2.w^tw)
                | (a3.x^tw)|(a3.y^tw)|(a3.z^tw)|(a3.w^tw);
        if (__all((bad & 0xffff0000u) == 0u)) break;
        __builtin_amdgcn_s_sleep(1);
        a0 = ld16s(hb); a1 = ld16s(hb+4); a2 = ld16s(hb+8); a3 = ld16s(hb+12);
        waitv0();
      }
      // pack 16 tagged words -> 16 bf16, stage to LDS
      u32x4 p0, p1;
      p0.x = __builtin_amdgcn_perm(a0.y, a0.x, 0x05040100u);
      p0.y = __builtin_amdgcn_perm(a0.w, a0.z, 0x05040100u);
      p0.z = __builtin_amdgcn_perm(a1.y, a1.x, 0x05040100u);
      p0.w = __builtin_amdgcn_perm(a1.w, a1.z, 0x05040100u);
      p1.x = __builtin_amdgcn_perm(a2.y, a2.x, 0x05040100u);
      p1.y = __builtin_amdgcn_perm(a2.w, a2.z, 0x05040100u);
      p1.z = __builtin_amdgcn_perm(a3.y, a3.x, 0x05040100u);
      p1.w = __builtin_amdgcn_perm(a3.w, a3.z, 0x05040100u);
      *(u32x4*)&hsh[tid>>5][(tid&31)*16]     = p0;
      *(u32x4*)&hsh[tid>>5][(tid&31)*16 + 8] = p1;
      bar_raw();   // [A2] hsh complete

      // A-frags from LDS, apply zh in-register, h-MFMAs
      #pragma unroll
      for (int c = 0; c < 8; c++){
        u32x4 hr = *(const u32x4*)&hsh[arow][qh*256 + c*32 + kq*8];
        u32x4 hm;
        hm.x = bpack(blo(hr.x)*blo(zf[c].x), bhi(hr.x)*bhi(zf[c].x));
        hm.y = bpack(blo(hr.y)*blo(zf[c].y), bhi(hr.y)*bhi(zf[c].y));
        hm.z = bpack(blo(hr.z)*blo(zf[c].z), bhi(hr.z)*bhi(zf[c].z));
        hm.w = bpack(blo(hr.w)*blo(zf[c].w), bhi(hr.w)*bhi(zf[c].w));
        acc0 = __builtin_amdgcn_mfma_f32_16x16x32_bf16(as_b8(hm), as_b8(whf[0][c]), acc0, 0,0,0);
        acc1 = __builtin_amdgcn_mfma_f32_16x16x32_bf16(as_b8(hm), as_b8(whf[1][c]), acc1, 0,0,0);
      }
    } else {
      #pragma unroll
      for (int c = 0; c < 4; c++){
        acc0 = __builtin_amdgcn_mfma_f32_16x16x32_bf16(as_b8(xa[c]), as_b8(wxf[0][c]), acc0, 0,0,0);
        acc1 = __builtin_amdgcn_mfma_f32_16x16x32_bf16(as_b8(xa[c]), as_b8(wxf[1][c]), acc1, 0,0,0);
      }
    }

    // D-frag: b_local = kq*4+r, k_local = nt*16 + arow
    #pragma unroll
    for (int r = 0; r < 4; r++){
      pl[wid][kq*4 + r][arow]      = acc0[r];
      pl[wid][kq*4 + r][16 + arow] = acc1[r];
    }
    bar_raw();   // [B] pl complete

    { // epilogue: all 512 threads, one (b,k) cell each
      float gv[4];
      #pragma unroll
      for (int gg = 0; gg < 4; gg++)
        gv[gg] = pl[gg][ebl][ekl] + pl[4+gg][ebl][ekl] + bias4[gg];
      float iv = 1.f/(1.f + __expf(-gv[0]));
      float fv = 1.f/(1.f + __expf(-gv[1]));
      float ov = 1.f/(1.f + __expf(-gv[2]));
      float e2g = __expf(2.f*gv[3]);
      float gc = 1.f - 2.f/(e2g + 1.f);          // tanh(g)
      creg = fv*creg + iv*gc;
      float e2c = __expf(2.f*creg);
      float th = 1.f - 2.f/(e2c + 1.f);          // tanh(c)
      float hv = ov*th;

      // xa prefetch for t+1 FIRST (oldest of the new batch)
      if (t+1 < TT){
        #pragma unroll
        for (int c = 0; c < 4; c++)
          xa[c] = ld16p(xim + ((((size_t)(t+1)*4 + g)*BB + b0 + arow)*DD
                               + qh*128 + c*32 + kq*8));
      }
      // ONE tagged raw-h store (issue-only) + hn output
      st4s(hmraw + ((size_t)(t&1)*NBG + bg)*(16*HH) + ebl*HH + k0 + ekl,
           ((u32)t << 16) | (u32)f2b(hv));
      st4p(hn + (size_t)t*BB*HH + (size_t)(b0 + ebl)*HH + k0 + ekl,
           __float_as_uint(hv));
      if (t == TT-1){
        const size_t ci = (size_t)(b0 + ebl)*HH + k0 + ekl;
        htc[ci] = hv;
        htc[(size_t)BB*HH + ci] = creg;
      }
      // speculative data read for t+1 (NEWEST 4 in queue -> next waitv4
      // keeps exactly these in flight). Safety: tags carry the truth;
      // buffer-reuse induction unchanged by early issue.
      if (t+1 < TT){
        const u32* hb2 = hmraw + ((size_t)(t&1)*NBG + bg)*(16*HH) + tid*16;
        a0 = ld16s(hb2); a1 = ld16s(hb2+4); a2 = ld16s(hb2+8); a3 = ld16s(hb2+12);
      }
    }
    // no [C]: verify(t+1) requires own-block tag stores, which follow all
    // pl/hsh reads in program order -> LDS reuse is ordered without it.
  }
}

// ---------------------------------------------------------------------------
extern "C" void kernel_launch(void* const* d_in, const int* in_sizes, int n_in,
                              void* d_out, int out_size, void* d_ws, size_t ws_size,
                              hipStream_t stream){
  const float* input   = (const float*)d_in[0];
  const float* ux      = (const float*)d_in[1];
  const float* uh      = (const float*)d_in[2];
  const float* p_logit = (const float*)d_in[3];
  const float* Wx      = (const float*)d_in[4];
  const float* bx      = (const float*)d_in[5];
  const float* Wh      = (const float*)d_in[6];
  const float* bh      = (const float*)d_in[7];

  char* ws = (char*)d_ws;
  const size_t o_zx  = 0;                        // 4*B*D f32      = 524288
  const size_t o_zh  = o_zx  + 524288;           // 4*B*H f32      = 1048576
  const size_t o_b   = o_zh  + 1048576;          // 4*H f32        = 8192
  const size_t o_wxb = o_b   + 8192;             // 4*H*D bf16     = 1048576
  const size_t o_whb = o_wxb + 1048576;          // 4*H*H bf16     = 2097152
  const size_t o_xim = o_whb + 2097152;          // T*4*B*D bf16   = 134217728
  const size_t o_hm  = o_xim + 134217728;        // 2*8*16*H u32   = 524288
  const size_t need  = o_hm + 524288;
  if (ws_size < need) return;

  float* zx   = (float*)(ws + o_zx);
  float* zh   = (float*)(ws + o_zh);
  float* bias = (float*)(ws + o_b);
  u16*   wxb  = (u16*)(ws + o_wxb);
  u16*   whb  = (u16*)(ws + o_whb);
  u16*   xim  = (u16*)(ws + o_xim);
  u32*   hmraw= (u32*)(ws + o_hm);

  float* out_hn = (float*)d_out;
  float* out_ht = out_hn + (size_t)TT*BB*HH;

  setup_kernel<<<8200, 256, 0, stream>>>(ux, uh, p_logit, bx, bh, Wx, Wh,
                                         zx, zh, bias, wxb, whb, hmraw);
  xim_kernel<<<8192, 256, 0, stream>>>(input, zx, xim);
  lstm_persist<<<NBG*NKS, 512, 0, stream>>>(xim, whb, wxb, zh, bias,
                                            hmraw, out_hn, out_ht);
}

// Round 17
// 1550.777 us; speedup vs baseline: 1.3216x; 1.3216x over previous
//
#include <hip/hip_runtime.h>
#include <hip/hip_bf16.h>
#include <math.h>

#define TT 512
#define BB 128
#define DD 256
#define HH 512
#define EPSF 1e-7f
#define NBG 8     // b-groups of 16 rows (independent LSTM chains)
#define NKS 16    // k-slices of 32 cols per b-group

typedef unsigned int u32;
typedef unsigned short u16;
typedef __attribute__((ext_vector_type(8))) short bf16x8;
typedef __attribute__((ext_vector_type(4))) float f32x4;
typedef __attribute__((ext_vector_type(4))) u32 u32x4;

__device__ __forceinline__ u16 f2b(float x){
  __hip_bfloat16 b = __float2bfloat16(x);
  union { __hip_bfloat16 h; u16 u; } c; c.h = b; return c.u;
}
__device__ __forceinline__ bf16x8 as_b8(u32x4 u){
  union { u32x4 a; bf16x8 b; } c; c.a = u; return c.b;
}
__device__ __forceinline__ float blo(u32 u){ return __uint_as_float(u << 16); }
__device__ __forceinline__ float bhi(u32 u){ return __uint_as_float(u & 0xffff0000u); }
__device__ __forceinline__ u32 bpack(float lo, float hi){
  return ((u32)f2b(hi) << 16) | (u32)f2b(lo);
}
// MALL-coherent ops (bypass L1+L2 both ways; zero cache-maintenance anywhere)
__device__ __forceinline__ u32x4 ld16s(const void* p){
  u32x4 r;
  asm volatile("global_load_dwordx4 %0, %1, off sc0 sc1" : "=v"(r) : "v"(p) : "memory");
  return r;
}
__device__ __forceinline__ void st4s(void* p, u32 v){
  asm volatile("global_store_dword %0, %1, off sc0 sc1" :: "v"(p), "v"(v) : "memory");
}
// plain cached ops (hand-counted vmem)
__device__ __forceinline__ u32x4 ld16p(const void* p){
  u32x4 r;
  asm volatile("global_load_dwordx4 %0, %1, off" : "=v"(r) : "v"(p) : "memory");
  return r;
}
__device__ __forceinline__ void st4p(void* p, u32 v){
  asm volatile("global_store_dword %0, %1, off" :: "v"(p), "v"(v) : "memory");
}
__device__ __forceinline__ void waitv0(){
  asm volatile("s_waitcnt vmcnt(0)" ::: "memory");
  __builtin_amdgcn_sched_barrier(0);
}
// retire everything older than the 4 just-issued data loads (4 xa + 2 stores)
__device__ __forceinline__ void waitv4(){
  asm volatile("s_waitcnt vmcnt(4)" ::: "memory");
  __builtin_amdgcn_sched_barrier(0);
}
// raw barrier: LDS visibility only — never drains vmcnt
__device__ __forceinline__ void bar_raw(){
  asm volatile("s_waitcnt lgkmcnt(0)" ::: "memory");
  __builtin_amdgcn_sched_barrier(0);
  __builtin_amdgcn_s_barrier();
  __builtin_amdgcn_sched_barrier(0);
}

// ---------------------------------------------------------------------------
// Setup: masks zx/zh, combined bias, bf16 Wx/Wh, hmraw tag-invalidation.
// ---------------------------------------------------------------------------
__global__ void setup_kernel(const float* __restrict__ ux, const float* __restrict__ uh,
                             const float* __restrict__ p_logit,
                             const float* __restrict__ bx, const float* __restrict__ bh,
                             const float* __restrict__ Wx, const float* __restrict__ Wh,
                             float* __restrict__ zx, float* __restrict__ zh,
                             float* __restrict__ bias,
                             u16* __restrict__ wxb, u16* __restrict__ whb,
                             u32* __restrict__ hmraw){
  const int i = blockIdx.x*256 + threadIdx.x;
  const float p = 1.0f/(1.0f+expf(-p_logit[0]));
  const float lp = logf(p+EPSF) - logf(1.0f-p+EPSF);
  const float inv1mp = 1.0f/(1.0f-p);
  const int S1 = 4*BB*DD;             // zx end      131072
  const int S2 = S1 + 4*BB*HH;        // zh end      393216
  const int S3 = S2 + 4*HH;           // bias end    395264
  const int S4 = S3 + 4*HH*DD;        // wxb end     919552
  const int S5 = S4 + 4*HH*HH;        // whb end     1968128
  const int S6 = S5 + 2*NBG*16*HH;    // hmraw end   2099200
  if (i < S1){
    float u = ux[i];
    float l = (lp + logf(u+EPSF) - logf(1.0f-u+EPSF)) * 10.0f;  // /TEMP
    zx[i] = (1.0f - 1.0f/(1.0f+expf(-l))) * inv1mp;
  } else if (i < S2){
    int j = i - S1;
    float u = uh[j];
    float l = (lp + logf(u+EPSF) - logf(1.0f-u+EPSF)) * 10.0f;
    zh[j] = (1.0f - 1.0f/(1.0f+expf(-l))) * inv1mp;
  } else if (i < S3){
    int j = i - S2;
    bias[j] = bx[j] + bh[j];
  } else if (i < S4){
    int j = i - S3;
    wxb[j] = f2b(Wx[j]);
  } else if (i < S5){
    int j = i - S4;
    whb[j] = f2b(Wh[j]);
  } else if (i < S6){
    hmraw[i - S5] = 0xFFFF0000u;   // invalid tag (kills cross-replay ghosts)
  }
}

// ---------------------------------------------------------------------------
// xim[t][g][b][d] = bf16(input[t][b][d] * zx[g][b][d]); input read once.
// ---------------------------------------------------------------------------
__global__ void xim_kernel(const float* __restrict__ input, const float* __restrict__ zx,
                           u16* __restrict__ xim){
  const int i = blockIdx.x*256 + threadIdx.x;   // (t,b,d-octet)
  const int d = (i & 31) * 8;
  const int rest = i >> 5;             // t*BB + b
  const int b = rest & (BB-1);
  const int t = rest >> 7;
  const float* ip = input + ((size_t)t*BB + b)*DD + d;
  const float4 x0 = *(const float4*)ip;
  const float4 x1 = *(const float4*)(ip+4);
  #pragma unroll
  for (int g = 0; g < 4; g++){
    const float* zp = zx + ((size_t)g*BB + b)*DD + d;
    const float4 z0 = *(const float4*)zp;
    const float4 z1 = *(const float4*)(zp+4);
    union { u16 s[8]; uint4 v; } o;
    o.s[0]=f2b(x0.x*z0.x); o.s[1]=f2b(x0.y*z0.y); o.s[2]=f2b(x0.z*z0.z); o.s[3]=f2b(x0.w*z0.w);
    o.s[4]=f2b(x1.x*z1.x); o.s[5]=f2b(x1.y*z1.y); o.s[6]=f2b(x1.z*z1.z); o.s[7]=f2b(x1.w*z1.w);
    *(uint4*)(xim + (((size_t)t*4 + g)*BB + b)*DD + d) = o.v;
  }
}

// ---------------------------------------------------------------------------
// Persistent LSTM: r12's cooperative raw-h data plane (32KB/block/step + LDS
// dedup), detection FUSED into the cooperative read via tags (digest gone).
// 128 blocks = 8 bg x 16 ks; 512 thr = 8 waves = (gate g) x (K-half qh).
// Step top: each thread issues its 4 tagged 16B loads; waitv4 retires older
// xa+stores; x-MFMAs overlap flight; waitv0; verify tags; paced wave-local
// 64B retry. Then stage->LDS, zh in-register, h-MFMAs. Producer: ONE tagged
// raw-h store/thread (issue-only, no drain, no flag).
// ---------------------------------------------------------------------------
__global__ __launch_bounds__(512, 2)
void lstm_persist(const u16* __restrict__ xim,   // [T][4][B][D]
                  const u16* __restrict__ whb,   // [4][H][H]
                  const u16* __restrict__ wxb,   // [4][H][D]
                  const float* __restrict__ zh,  // [4][B][H]
                  const float* __restrict__ bias,// [4][H]
                  u32* __restrict__ hmraw,       // [2][NBG][16][H] tagged h
                  float* __restrict__ hn,        // [T][B][H]
                  float* __restrict__ htc)       // [2][B][H]
{
  __shared__ float pl[8][16][36];               // partial gates (padded)
  __shared__ __align__(16) u16 hsh[16][520];    // shared h(t-1) bf16 (padded)

  const int bid = blockIdx.x;
  const int bg = bid & 7, ks = bid >> 3;
  const int b0 = bg*16, k0 = ks*32;
  const int tid = threadIdx.x;
  const int wid = tid >> 6, lane = tid & 63;
  const int g = wid & 3, qh = wid >> 2;
  const int arow = lane & 15, kq = lane >> 4;

  // ---- weights into registers ----
  u32x4 whf[2][8], wxf[2][4];
  #pragma unroll
  for (int nt = 0; nt < 2; nt++){
    #pragma unroll
    for (int c = 0; c < 8; c++)
      whf[nt][c] = *(const u32x4*)(whb + (((size_t)g*HH + k0 + nt*16 + arow)*HH
                                          + qh*256 + c*32 + kq*8));
    #pragma unroll
    for (int c = 0; c < 4; c++)
      wxf[nt][c] = *(const u32x4*)(wxb + (((size_t)g*HH + k0 + nt*16 + arow)*DD
                                          + qh*128 + c*32 + kq*8));
  }

  // zh for this wave's A-slice, packed bf16 (proven in r12)
  u32x4 zf[8];
  {
    const float* zp = zh + ((size_t)g*BB + b0 + arow)*HH + qh*256 + kq*8;
    #pragma unroll
    for (int c = 0; c < 8; c++){
      zf[c].x = bpack(zp[c*32+0], zp[c*32+1]);
      zf[c].y = bpack(zp[c*32+2], zp[c*32+3]);
      zf[c].z = bpack(zp[c*32+4], zp[c*32+5]);
      zf[c].w = bpack(zp[c*32+6], zp[c*32+7]);
    }
  }

  // per-thread epilogue constants (1 cell per thread)
  const int ebl = tid >> 5, ekl = tid & 31;
  float bias4[4];
  #pragma unroll
  for (int gg = 0; gg < 4; gg++)
    bias4[gg] = bias[gg*HH + k0 + ekl];
  float creg = 0.f;

  // prologue: xa for t=0
  u32x4 xa[4];
  #pragma unroll
  for (int c = 0; c < 4; c++)
    xa[c] = ld16p(xim + (((size_t)g*BB + b0 + arow)*DD + qh*128 + c*32 + kq*8));
  waitv0();

  for (int t = 0; t < TT; t++){
    f32x4 acc0 = {0.f,0.f,0.f,0.f}, acc1 = {0.f,0.f,0.f,0.f};

    if (t > 0){
      // speculative cooperative read: 64B/thread of tagged raw h(t-1)
      const u32* hb = hmraw + ((size_t)((t-1)&1)*NBG + bg)*(16*HH) + tid*16;
      u32x4 a0 = ld16s(hb), a1 = ld16s(hb+4), a2 = ld16s(hb+8), a3 = ld16s(hb+12);
      waitv4();    // retires xa(4) + 2 stores (older); data stays in flight
      #pragma unroll
      for (int c = 0; c < 4; c++){
        acc0 = __builtin_amdgcn_mfma_f32_16x16x32_bf16(as_b8(xa[c]), as_b8(wxf[0][c]), acc0, 0,0,0);
        acc1 = __builtin_amdgcn_mfma_f32_16x16x32_bf16(as_b8(xa[c]), as_b8(wxf[1][c]), acc1, 0,0,0);
      }
      waitv0();    // data landed
      const u32 tw = (u32)(t-1) << 16;
      while (1){   // tags ARE the detection; paced wave-local retry
        u32 bad = (a0.x^tw)|(a0.y^tw)|(a0.z^tw)|(a0.w^tw)
                | (a1.x^tw)|(a1.y^tw)|(a1.z^tw)|(a1.w^tw)
                | (a2.x^tw)|(a2.y^tw)|(a2.z^tw)|(a2.w^tw)
                | (a3.x^tw)|(a3.y^tw)|(a3.z^tw)|(a3.w^tw);
        if (__all((bad & 0xffff0000u) == 0u)) break;
        __builtin_amdgcn_s_sleep(2);
        a0 = ld16s(hb); a1 = ld16s(hb+4); a2 = ld16s(hb+8); a3 = ld16s(hb+12);
        waitv0();
      }
      // pack 16 tagged words -> 16 bf16, stage to LDS (r12 mapping)
      u32x4 p0, p1;
      p0.x = __builtin_amdgcn_perm(a0.y, a0.x, 0x05040100u);
      p0.y = __builtin_amdgcn_perm(a0.w, a0.z, 0x05040100u);
      p0.z = __builtin_amdgcn_perm(a1.y, a1.x, 0x05040100u);
      p0.w = __builtin_amdgcn_perm(a1.w, a1.z, 0x05040100u);
      p1.x = __builtin_amdgcn_perm(a2.y, a2.x, 0x05040100u);
      p1.y = __builtin_amdgcn_perm(a2.w, a2.z, 0x05040100u);
      p1.z = __builtin_amdgcn_perm(a3.y, a3.x, 0x05040100u);
      p1.w = __builtin_amdgcn_perm(a3.w, a3.z, 0x05040100u);
      *(u32x4*)&hsh[tid>>5][(tid&31)*16]     = p0;
      *(u32x4*)&hsh[tid>>5][(tid&31)*16 + 8] = p1;
      bar_raw();   // [A2] hsh complete

      // A-frags from LDS, apply zh in-register, h-MFMAs (r12 path, proven)
      #pragma unroll
      for (int c = 0; c < 8; c++){
        u32x4 hr = *(const u32x4*)&hsh[arow][qh*256 + c*32 + kq*8];
        u32x4 hm;
        hm.x = bpack(blo(hr.x)*blo(zf[c].x), bhi(hr.x)*bhi(zf[c].x));
        hm.y = bpack(blo(hr.y)*blo(zf[c].y), bhi(hr.y)*bhi(zf[c].y));
        hm.z = bpack(blo(hr.z)*blo(zf[c].z), bhi(hr.z)*bhi(zf[c].z));
        hm.w = bpack(blo(hr.w)*blo(zf[c].w), bhi(hr.w)*bhi(zf[c].w));
        acc0 = __builtin_amdgcn_mfma_f32_16x16x32_bf16(as_b8(hm), as_b8(whf[0][c]), acc0, 0,0,0);
        acc1 = __builtin_amdgcn_mfma_f32_16x16x32_bf16(as_b8(hm), as_b8(whf[1][c]), acc1, 0,0,0);
      }
    } else {
      #pragma unroll
      for (int c = 0; c < 4; c++){
        acc0 = __builtin_amdgcn_mfma_f32_16x16x32_bf16(as_b8(xa[c]), as_b8(wxf[0][c]), acc0, 0,0,0);
        acc1 = __builtin_amdgcn_mfma_f32_16x16x32_bf16(as_b8(xa[c]), as_b8(wxf[1][c]), acc1, 0,0,0);
      }
    }

    // D-frag: b_local = kq*4+r, k_local = nt*16 + arow
    #pragma unroll
    for (int r = 0; r < 4; r++){
      pl[wid][kq*4 + r][arow]      = acc0[r];
      pl[wid][kq*4 + r][16 + arow] = acc1[r];
    }
    bar_raw();   // [B] pl complete

    { // epilogue: all 512 threads, one (b,k) cell each
      float gv[4];
      #pragma unroll
      for (int gg = 0; gg < 4; gg++)
        gv[gg] = pl[gg][ebl][ekl] + pl[4+gg][ebl][ekl] + bias4[gg];
      float iv = 1.f/(1.f + __expf(-gv[0]));
      float fv = 1.f/(1.f + __expf(-gv[1]));
      float ov = 1.f/(1.f + __expf(-gv[2]));
      float e2g = __expf(2.f*gv[3]);
      float gc = 1.f - 2.f/(e2g + 1.f);          // tanh(g)
      creg = fv*creg + iv*gc;
      float e2c = __expf(2.f*creg);
      float th = 1.f - 2.f/(e2c + 1.f);          // tanh(c)
      float hv = ov*th;

      // xa prefetch for t+1 FIRST (oldest), then the 2 stores
      if (t+1 < TT){
        #pragma unroll
        for (int c = 0; c < 4; c++)
          xa[c] = ld16p(xim + ((((size_t)(t+1)*4 + g)*BB + b0 + arow)*DD
                               + qh*128 + c*32 + kq*8));
      }
      // ONE tagged raw-h store (issue-only) + hn output
      st4s(hmraw + ((size_t)(t&1)*NBG + bg)*(16*HH) + ebl*HH + k0 + ekl,
           ((u32)t << 16) | (u32)f2b(hv));
      st4p(hn + (size_t)t*BB*HH + (size_t)(b0 + ebl)*HH + k0 + ekl,
           __float_as_uint(hv));
      if (t == TT-1){
        const size_t ci = (size_t)(b0 + ebl)*HH + k0 + ekl;
        htc[ci] = hv;
        htc[(size_t)BB*HH + ci] = creg;
      }
    }
    bar_raw();   // [C] pl/hsh reads done; stores issued block-wide
  }
}

// ---------------------------------------------------------------------------
extern "C" void kernel_launch(void* const* d_in, const int* in_sizes, int n_in,
                              void* d_out, int out_size, void* d_ws, size_t ws_size,
                              hipStream_t stream){
  const float* input   = (const float*)d_in[0];
  const float* ux      = (const float*)d_in[1];
  const float* uh      = (const float*)d_in[2];
  const float* p_logit = (const float*)d_in[3];
  const float* Wx      = (const float*)d_in[4];
  const float* bx      = (const float*)d_in[5];
  const float* Wh      = (const float*)d_in[6];
  const float* bh      = (const float*)d_in[7];

  char* ws = (char*)d_ws;
  const size_t o_zx  = 0;                        // 4*B*D f32      = 524288
  const size_t o_zh  = o_zx  + 524288;           // 4*B*H f32      = 1048576
  const size_t o_b   = o_zh  + 1048576;          // 4*H f32        = 8192
  const size_t o_wxb = o_b   + 8192;             // 4*H*D bf16     = 1048576
  const size_t o_whb = o_wxb + 1048576;          // 4*H*H bf16     = 2097152
  const size_t o_xim = o_whb + 2097152;          // T*4*B*D bf16   = 134217728
  const size_t o_hm  = o_xim + 134217728;        // 2*8*16*H u32   = 524288
  const size_t need  = o_hm + 524288;
  if (ws_size < need) return;

  float* zx   = (float*)(ws + o_zx);
  float* zh   = (float*)(ws + o_zh);
  float* bias = (float*)(ws + o_b);
  u16*   wxb  = (u16*)(ws + o_wxb);
  u16*   whb  = (u16*)(ws + o_whb);
  u16*   xim  = (u16*)(ws + o_xim);
  u32*   hmraw= (u32*)(ws + o_hm);

  float* out_hn = (float*)d_out;
  float* out_ht = out_hn + (size_t)TT*BB*HH;

  setup_kernel<<<8200, 256, 0, stream>>>(ux, uh, p_logit, bx, bh, Wx, Wh,
                                         zx, zh, bias, wxb, whb, hmraw);
  xim_kernel<<<8192, 256, 0, stream>>>(input, zx, xim);
  lstm_persist<<<NBG*NKS, 512, 0, stream>>>(xim, whb, wxb, zh, bias,
                                            hmraw, out_hn, out_ht);
}